// Round 6
// baseline (102.606 us; speedup 1.0000x reference)
//
#include <hip/hip_runtime.h>
#include <math.h>

#define SEQ 4096
#define NH  8
#define DIM 64
// 32 (n,h) pairs total: n=4, h=8

__device__ __forceinline__ float elu1(float x) {
    // jax.nn.elu(x)+1: branchless — exp(min(x,0)) + max(x,0)
    return __expf(fminf(x, 0.0f)) + fmaxf(x, 0.0f);
}

// ---------------- Phase 1: partial KV (64x64) + partial Ksum per (n,h,chunk) ----------------
// NO LDS staging, NO main-loop barriers (R5 showed the stage+vmcnt(0)+barrier
// structure exposed full HBM latency per 16-row tile -> 3.6x over floor).
// Each wave processes rows s = wv, wv+4, ... directly from global: the 8 lanes
// sharing d0/v0 read identical 16B chunks -> coalescer merges to one 256B row
// fetch; L1 broadcasts. 8 waves/CU free-run -> latency hidden by TLP.
// Cross-wave accumulator tree-reduce once at block end.
__global__ __launch_bounds__(256) void k_phase1(const float* __restrict__ Kin,
                                                const float* __restrict__ Vin,
                                                float* __restrict__ pKV,
                                                float* __restrict__ pKs,
                                                int NC, int sLen) {
    const int nh = blockIdx.x / NC;
    const int ck = blockIdx.x % NC;
    const int n  = nh >> 3, h = nh & 7;
    const int t  = threadIdx.x;
    const int wv   = t >> 6;        // wave 0..3
    const int lane = t & 63;
    const int d0 = (lane >> 3) * 8; // owned d block (8 rows of KV)
    const int v0 = (lane & 7) * 8;  // owned v block (8 cols)

    __shared__ __align__(16) float sred[4096];   // 16 KB cross-wave acc reduce
    __shared__ float ksred[256];                 // 1 KB cross-wave Ksum reduce

    float acc[8][8];
#pragma unroll
    for (int i = 0; i < 8; i++)
#pragma unroll
        for (int j = 0; j < 8; j++) acc[i][j] = 0.0f;
    float ks[8] = {0.f, 0.f, 0.f, 0.f, 0.f, 0.f, 0.f, 0.f};

    const int s0 = ck * sLen;
    const float* Kp = Kin + ((size_t)(n * SEQ + s0) * NH + h) * DIM;
    const float* Vp = Vin + ((size_t)(n * SEQ + s0) * NH + h) * DIM;

#pragma unroll 2
    for (int s = wv; s < sLen; s += 4) {
        const float* kr = Kp + (size_t)s * (NH * DIM);
        const float* vr = Vp + (size_t)s * (NH * DIM);
        float4 ka = *(const float4*)(kr + d0);
        float4 kb = *(const float4*)(kr + d0 + 4);
        float4 va = *(const float4*)(vr + v0);
        float4 vb = *(const float4*)(vr + v0 + 4);
        float a[8] = {elu1(ka.x), elu1(ka.y), elu1(ka.z), elu1(ka.w),
                      elu1(kb.x), elu1(kb.y), elu1(kb.z), elu1(kb.w)};
        float b[8] = {va.x, va.y, va.z, va.w, vb.x, vb.y, vb.z, vb.w};
#pragma unroll
        for (int i = 0; i < 8; i++) ks[i] += a[i];
#pragma unroll
        for (int i = 0; i < 8; i++)
#pragma unroll
            for (int j = 0; j < 8; j++)
                acc[i][j] = fmaf(a[i], b[j], acc[i][j]);
    }

    // Ksum partials: the 8 lanes sharing d0 hold identical ks; lane v0==0 writes.
    if ((lane & 7) == 0) {
#pragma unroll
        for (int i = 0; i < 8; i++) ksred[wv * 64 + d0 + i] = ks[i];
    }

    // cross-wave acc reduction: w3 -> w2 -> w1 -> w0 through sred (layout
    // elem*64+lane: bank = lane%32, 2 lanes/bank = free)
#pragma unroll
    for (int src = 3; src >= 1; --src) {
        __syncthreads();
        if (wv == src) {
#pragma unroll
            for (int i = 0; i < 8; i++)
#pragma unroll
                for (int j = 0; j < 8; j++) sred[(i * 8 + j) * 64 + lane] = acc[i][j];
        }
        __syncthreads();
        if (wv == src - 1) {
#pragma unroll
            for (int i = 0; i < 8; i++)
#pragma unroll
                for (int j = 0; j < 8; j++) acc[i][j] += sred[(i * 8 + j) * 64 + lane];
        }
    }

    // wave0 stores partial KV: pKV[(ck*32+nh)][d][v]
    if (wv == 0) {
        float* dst = pKV + ((size_t)ck * 32 + nh) * 4096;
#pragma unroll
        for (int i = 0; i < 8; i++) {
            float4 oa, ob;
            oa.x = acc[i][0]; oa.y = acc[i][1]; oa.z = acc[i][2]; oa.w = acc[i][3];
            ob.x = acc[i][4]; ob.y = acc[i][5]; ob.z = acc[i][6]; ob.w = acc[i][7];
            *(float4*)(dst + (d0 + i) * 64 + v0)     = oa;
            *(float4*)(dst + (d0 + i) * 64 + v0 + 4) = ob;
        }
    }

    // Ksum final (ksred visible since first reduce barrier)
    if (t < 64) {
        float s = ksred[t] + ksred[64 + t] + ksred[128 + t] + ksred[192 + t];
        pKs[((size_t)ck * 32 + nh) * 64 + t] = s;
    }
}

// ---------------- Reduce partials -> final KV, Ksum ----------------
template <int NC>
__global__ __launch_bounds__(128) void k_reduceT(const float* __restrict__ pKV,
                                                 const float* __restrict__ pKs,
                                                 float* __restrict__ KVf,
                                                 float* __restrict__ Ksf) {
    const int gid = blockIdx.x * 128 + threadIdx.x;   // 0..32767, one float4 each
    const float4* p4 = (const float4*)pKV;
    float4 s = make_float4(0.f, 0.f, 0.f, 0.f);
#pragma unroll
    for (int c = 0; c < NC; ++c) {
        float4 v = p4[(size_t)c * 32768 + gid];
        s.x += v.x; s.y += v.y; s.z += v.z; s.w += v.w;
    }
    ((float4*)KVf)[gid] = s;
    if (gid < 2048) {
        float ss = 0.0f;
#pragma unroll
        for (int c = 0; c < NC; ++c) ss += pKs[(size_t)c * 2048 + gid];
        Ksf[gid] = ss;
    }
}

__global__ __launch_bounds__(128) void k_reduceG(const float* __restrict__ pKV,
                                                 const float* __restrict__ pKs,
                                                 float* __restrict__ KVf,
                                                 float* __restrict__ Ksf, int NC) {
    const int gid = blockIdx.x * 128 + threadIdx.x;
    const float4* p4 = (const float4*)pKV;
    float4 s = make_float4(0.f, 0.f, 0.f, 0.f);
    for (int c = 0; c < NC; ++c) {
        float4 v = p4[(size_t)c * 32768 + gid];
        s.x += v.x; s.y += v.y; s.z += v.z; s.w += v.w;
    }
    ((float4*)KVf)[gid] = s;
    if (gid < 2048) {
        float ss = 0.0f;
        for (int c = 0; c < NC; ++c) ss += pKs[(size_t)c * 2048 + gid];
        Ksf[gid] = ss;
    }
}

// ---------------- Phase 2: register-tiled GEMM, out[l,v] = (Qf.KV[:,v]) / (Qf.Ks + eps) ----------------
// 512 blocks (32 nh x 16 tiles of 256 rows), 256 threads, 8x8 per-thread tile.
// T14 async-STAGE: chunk dc+1's Q loads issue into regs right after the
// consume barrier, LDS-write happens next iteration -> staging latency hides
// under the 16-dl compute. Swizzle widened to s=(dl&12)<<1: transpose writes
// now 2-way over all 32 banks (was 4-way over 16).
__global__ __launch_bounds__(256) void k_phase2(const float* __restrict__ Qin,
                                                const float* __restrict__ KVf,
                                                const float* __restrict__ Ksf,
                                                float* __restrict__ Out) {
    const int nh   = blockIdx.x >> 4;
    const int tile = blockIdx.x & 15;
    const int n = nh >> 3, h = nh & 7;
    const int t = threadIdx.x;

    __shared__ __align__(16) float Qt[16 * 256];   // 16 KB, swizzled transpose chunk
    __shared__ __align__(16) float KVs[64][64];    // 16 KB
    __shared__ float Kss[64];

    const int l0    = tile * 256;
    const int rbase = t >> 2;            // 0..63 (row within first i-slice)
    const int dl4   = (t & 3) << 2;      // 0,4,8,12
    const int colw  = rbase ^ (dl4 << 1);

    // issue chunk-0 Q loads first (overlap with KV staging)
    const float* qb = Qin + ((size_t)(n * SEQ + l0 + rbase) * NH + h) * DIM + dl4;
    float4 q0 = *(const float4*)(qb);
    float4 q1 = *(const float4*)(qb + 32768);    // +64 rows * 512
    float4 q2 = *(const float4*)(qb + 65536);
    float4 q3 = *(const float4*)(qb + 98304);

    // stage KV + Ksum (coalesced; small, L2/L3-resident)
    {
        const float4* src = (const float4*)(KVf + (size_t)nh * 4096);
        float4* dst = (float4*)&KVs[0][0];
#pragma unroll
        for (int i = 0; i < 4; ++i) dst[t + 256 * i] = src[t + 256 * i];
        if (t < 64) Kss[t] = Ksf[nh * 64 + t];
    }

    const int r0 = (t >> 3) * 8;     // owned rows (8)
    const int v0 = (t & 7) * 8;      // owned cols (8)

    float acc[8][8];
#pragma unroll
    for (int i = 0; i < 8; i++)
#pragma unroll
        for (int j = 0; j < 8; j++) acc[i][j] = 0.0f;
    float p[8] = {0.f, 0.f, 0.f, 0.f, 0.f, 0.f, 0.f, 0.f};

    for (int dc = 0; dc < 4; ++dc) {
        // write current chunk's regs -> Qt (transposed, swizzled, elu applied)
#pragma unroll
        for (int k = 0; k < 4; ++k) {
            float e0 = elu1(k == 0 ? q0.x : k == 1 ? q0.y : k == 2 ? q0.z : q0.w);
            float e1 = elu1(k == 0 ? q1.x : k == 1 ? q1.y : k == 2 ? q1.z : q1.w);
            float e2 = elu1(k == 0 ? q2.x : k == 1 ? q2.y : k == 2 ? q2.z : q2.w);
            float e3 = elu1(k == 0 ? q3.x : k == 1 ? q3.y : k == 2 ? q3.z : q3.w);
            float* row = &Qt[(dl4 + k) * 256 + colw];
            row[0]   = e0;
            row[64]  = e1;
            row[128] = e2;
            row[192] = e3;
        }
        __syncthreads();
        if (dc < 3) {                       // prefetch next chunk into regs
            const float* qn = qb + (dc + 1) * 16;
            q0 = *(const float4*)(qn);
            q1 = *(const float4*)(qn + 32768);
            q2 = *(const float4*)(qn + 65536);
            q3 = *(const float4*)(qn + 98304);
        }

#pragma unroll 2
        for (int dl = 0; dl < 16; ++dl) {
            const int d = dc * 16 + dl;
            const int s = (dl & 12) << 1;
            float4 qa = *(const float4*)&Qt[dl * 256 + (r0 ^ s)];
            float4 qc = *(const float4*)&Qt[dl * 256 + ((r0 + 4) ^ s)];
            float4 ka = *(const float4*)&KVs[d][v0];
            float4 kb = *(const float4*)&KVs[d][v0 + 4];
            const float ksd = Kss[d];
            float q[8]  = {qa.x, qa.y, qa.z, qa.w, qc.x, qc.y, qc.z, qc.w};
            float kv[8] = {ka.x, ka.y, ka.z, ka.w, kb.x, kb.y, kb.z, kb.w};
#pragma unroll
            for (int i = 0; i < 8; ++i) {
                p[i] = fmaf(q[i], ksd, p[i]);
#pragma unroll
                for (int jj = 0; jj < 8; ++jj)
                    acc[i][jj] = fmaf(q[i], kv[jj], acc[i][jj]);
            }
        }
        if (dc < 3) __syncthreads();   // Qt reads done before next overwrite
    }

    // epilogue: scale by 1/(p+eps), float4 stores
#pragma unroll
    for (int i = 0; i < 8; ++i) {
        const float z = 1.0f / (p[i] + 1e-6f);
        const int l = l0 + r0 + i;
        float* o = Out + ((size_t)(n * SEQ + l) * NH + h) * DIM + v0;
        float4 oa, ob;
        oa.x = acc[i][0] * z; oa.y = acc[i][1] * z; oa.z = acc[i][2] * z; oa.w = acc[i][3] * z;
        ob.x = acc[i][4] * z; ob.y = acc[i][5] * z; ob.z = acc[i][6] * z; ob.w = acc[i][7] * z;
        *(float4*)(o)     = oa;
        *(float4*)(o + 4) = ob;
    }
}

extern "C" void kernel_launch(void* const* d_in, const int* in_sizes, int n_in,
                              void* d_out, int out_size, void* d_ws, size_t ws_size,
                              hipStream_t stream) {
    const float* Q = (const float*)d_in[0];
    const float* K = (const float*)d_in[1];
    const float* V = (const float*)d_in[2];
    float* out = (float*)d_out;

    // ws layout: [KVf 32*4096][Ksf 32*64][pKV NC*32*4096][pKs NC*32*64]
    int NC = 16;  // 512 phase1 blocks (2/CU, 8 waves for TLP latency hiding)
    const size_t unit = 133120ull * 4ull; // (4096+64)*32 floats in bytes
    while (NC > 1 && (size_t)(NC + 1) * unit > ws_size) NC >>= 1;
    const int sLen = SEQ / NC;

    float* KVf = (float*)d_ws;
    float* Ksf = KVf + 32 * 4096;
    float* pKV = Ksf + 32 * 64;
    float* pKs = pKV + (size_t)NC * 32 * 4096;

    hipLaunchKernelGGL(k_phase1, dim3(32 * NC), dim3(256), 0, stream, K, V, pKV, pKs, NC, sLen);
    switch (NC) {
        case 32: hipLaunchKernelGGL(k_reduceT<32>, dim3(256), dim3(128), 0, stream, pKV, pKs, KVf, Ksf); break;
        case 16: hipLaunchKernelGGL(k_reduceT<16>, dim3(256), dim3(128), 0, stream, pKV, pKs, KVf, Ksf); break;
        case 8:  hipLaunchKernelGGL(k_reduceT<8>,  dim3(256), dim3(128), 0, stream, pKV, pKs, KVf, Ksf); break;
        default: hipLaunchKernelGGL(k_reduceG, dim3(256), dim3(128), 0, stream, pKV, pKs, KVf, Ksf, NC); break;
    }
    hipLaunchKernelGGL(k_phase2, dim3(512), dim3(256), 0, stream, Q, KVf, Ksf, out);
}

// Round 7
// 83.238 us; speedup vs baseline: 1.2327x; 1.2327x over previous
//
#include <hip/hip_runtime.h>
#include <math.h>

#define SEQ 4096
#define NH  8
#define DIM 64
// 32 (n,h) pairs total: n=4, h=8

__device__ __forceinline__ float elu1(float x) {
    // jax.nn.elu(x)+1: branchless — exp(min(x,0)) + max(x,0)
    return __expf(fminf(x, 0.0f)) + fmaxf(x, 0.0f);
}

// ---------------- Phase 1: partial KV (64x64) + partial Ksum per (n,h,chunk) ----------------
// h-FUSED streaming: block = (n, s-chunk), 512 thr = 8 waves, wave w = head w.
// The 8 waves advance through s together, so the block reads K[n,s,0:8,:] and
// V[n,s,0:8,:] as CONTIGUOUS 2KB segments per s (R6's failure was each wave
// touching 256B per 2KB stride -> 310 GB/s). Zero LDS, zero barriers; each
// wave owns a distinct (n,h) so it writes its own pKV partial directly.
// Software pipeline: row s+1 loads issue before row s compute.
__global__ __launch_bounds__(512) void k_phase1(const float* __restrict__ Kin,
                                                const float* __restrict__ Vin,
                                                float* __restrict__ pKV,
                                                float* __restrict__ pKs,
                                                int NC, int sLen) {
    const int n  = blockIdx.x / NC;
    const int ck = blockIdx.x % NC;
    const int t  = threadIdx.x;
    const int h    = t >> 6;        // wave id = head
    const int lane = t & 63;
    const int d0 = (lane >> 3) * 8; // owned d block (8)
    const int v0 = (lane & 7) * 8;  // owned v block (8)

    float acc[8][8];
#pragma unroll
    for (int i = 0; i < 8; i++)
#pragma unroll
        for (int j = 0; j < 8; j++) acc[i][j] = 0.0f;
    float ks[8] = {0.f, 0.f, 0.f, 0.f, 0.f, 0.f, 0.f, 0.f};

    const int s0 = ck * sLen;
    const int rs = NH * DIM;        // 512 floats per s-row
    const float* Kp = Kin + ((size_t)(n * SEQ + s0) * NH + h) * DIM;
    const float* Vp = Vin + ((size_t)(n * SEQ + s0) * NH + h) * DIM;

    float4 ka = *(const float4*)(Kp + d0);
    float4 kb = *(const float4*)(Kp + d0 + 4);
    float4 va = *(const float4*)(Vp + v0);
    float4 vb = *(const float4*)(Vp + v0 + 4);

#pragma unroll 2
    for (int s = 0; s < sLen - 1; ++s) {
        const float* kn = Kp + (size_t)(s + 1) * rs;
        const float* vn = Vp + (size_t)(s + 1) * rs;
        float4 nka = *(const float4*)(kn + d0);
        float4 nkb = *(const float4*)(kn + d0 + 4);
        float4 nva = *(const float4*)(vn + v0);
        float4 nvb = *(const float4*)(vn + v0 + 4);

        float a[8] = {elu1(ka.x), elu1(ka.y), elu1(ka.z), elu1(ka.w),
                      elu1(kb.x), elu1(kb.y), elu1(kb.z), elu1(kb.w)};
        float b[8] = {va.x, va.y, va.z, va.w, vb.x, vb.y, vb.z, vb.w};
#pragma unroll
        for (int i = 0; i < 8; i++) ks[i] += a[i];
#pragma unroll
        for (int i = 0; i < 8; i++)
#pragma unroll
            for (int j = 0; j < 8; j++)
                acc[i][j] = fmaf(a[i], b[j], acc[i][j]);

        ka = nka; kb = nkb; va = nva; vb = nvb;
    }
    {   // last row
        float a[8] = {elu1(ka.x), elu1(ka.y), elu1(ka.z), elu1(ka.w),
                      elu1(kb.x), elu1(kb.y), elu1(kb.z), elu1(kb.w)};
        float b[8] = {va.x, va.y, va.z, va.w, vb.x, vb.y, vb.z, vb.w};
#pragma unroll
        for (int i = 0; i < 8; i++) ks[i] += a[i];
#pragma unroll
        for (int i = 0; i < 8; i++)
#pragma unroll
            for (int j = 0; j < 8; j++)
                acc[i][j] = fmaf(a[i], b[j], acc[i][j]);
    }

    // store partial KV: pKV[(ck*32 + n*8+h)][d][v] — each wave a distinct slot
    const int nh = n * 8 + h;
    float* dst = pKV + ((size_t)ck * 32 + nh) * 4096;
#pragma unroll
    for (int i = 0; i < 8; i++) {
        float4 oa, ob;
        oa.x = acc[i][0]; oa.y = acc[i][1]; oa.z = acc[i][2]; oa.w = acc[i][3];
        ob.x = acc[i][4]; ob.y = acc[i][5]; ob.z = acc[i][6]; ob.w = acc[i][7];
        *(float4*)(dst + (d0 + i) * 64 + v0)     = oa;
        *(float4*)(dst + (d0 + i) * 64 + v0 + 4) = ob;
    }
    // Ksum: the 8 lanes sharing d0 hold identical ks; one lane per group writes
    if ((lane & 7) == 0) {
#pragma unroll
        for (int i = 0; i < 8; i++)
            pKs[((size_t)ck * 32 + nh) * 64 + d0 + i] = ks[i];
    }
}

// ---------------- Reduce partials -> final KV, Ksum ----------------
template <int NC>
__global__ __launch_bounds__(128) void k_reduceT(const float* __restrict__ pKV,
                                                 const float* __restrict__ pKs,
                                                 float* __restrict__ KVf,
                                                 float* __restrict__ Ksf) {
    const int gid = blockIdx.x * 128 + threadIdx.x;   // 0..32767, one float4 each
    const float4* p4 = (const float4*)pKV;
    float4 s = make_float4(0.f, 0.f, 0.f, 0.f);
#pragma unroll
    for (int c = 0; c < NC; ++c) {
        float4 v = p4[(size_t)c * 32768 + gid];
        s.x += v.x; s.y += v.y; s.z += v.z; s.w += v.w;
    }
    ((float4*)KVf)[gid] = s;
    if (gid < 2048) {
        float ss = 0.0f;
#pragma unroll
        for (int c = 0; c < NC; ++c) ss += pKs[(size_t)c * 2048 + gid];
        Ksf[gid] = ss;
    }
}

__global__ __launch_bounds__(128) void k_reduceG(const float* __restrict__ pKV,
                                                 const float* __restrict__ pKs,
                                                 float* __restrict__ KVf,
                                                 float* __restrict__ Ksf, int NC) {
    const int gid = blockIdx.x * 128 + threadIdx.x;
    const float4* p4 = (const float4*)pKV;
    float4 s = make_float4(0.f, 0.f, 0.f, 0.f);
    for (int c = 0; c < NC; ++c) {
        float4 v = p4[(size_t)c * 32768 + gid];
        s.x += v.x; s.y += v.y; s.z += v.z; s.w += v.w;
    }
    ((float4*)KVf)[gid] = s;
    if (gid < 2048) {
        float ss = 0.0f;
        for (int c = 0; c < NC; ++c) ss += pKs[(size_t)c * 2048 + gid];
        Ksf[gid] = ss;
    }
}

// ---------------- Phase 2: register-tiled GEMM, out[l,v] = (Qf.KV[:,v]) / (Qf.Ks + eps) ----------------
// (R4/R5-benched version, ~14.5us: 512 blocks, 8x8 per-thread tile, Qt chunked
// to 16 d-rows, swizzle col = row ^ (dl&12) -> <=2-way on writes and reads.)
__global__ __launch_bounds__(256) void k_phase2(const float* __restrict__ Qin,
                                                const float* __restrict__ KVf,
                                                const float* __restrict__ Ksf,
                                                float* __restrict__ Out) {
    const int nh   = blockIdx.x >> 4;
    const int tile = blockIdx.x & 15;
    const int n = nh >> 3, h = nh & 7;
    const int t = threadIdx.x;

    __shared__ __align__(16) float Qt[16 * 256];   // 16 KB, swizzled transpose chunk
    __shared__ __align__(16) float KVs[64][64];    // 16 KB
    __shared__ float Kss[64];

    // stage KV + Ksum (coalesced; small, L2/L3-resident)
    {
        const float4* src = (const float4*)(KVf + (size_t)nh * 4096);
        float4* dst = (float4*)&KVs[0][0];
#pragma unroll
        for (int i = 0; i < 4; ++i) dst[t + 256 * i] = src[t + 256 * i];
        if (t < 64) Kss[t] = Ksf[nh * 64 + t];
    }

    const int l0 = tile * 256;
    const int r0 = (t >> 3) * 8;     // owned rows (8), 0..248
    const int v0 = (t & 7) * 8;      // owned cols (8)

    float acc[8][8];
#pragma unroll
    for (int i = 0; i < 8; i++)
#pragma unroll
        for (int j = 0; j < 8; j++) acc[i][j] = 0.0f;
    float p[8] = {0.f, 0.f, 0.f, 0.f, 0.f, 0.f, 0.f, 0.f};

    for (int dc = 0; dc < 4; ++dc) {
        if (dc) __syncthreads();       // protect Qt before overwrite
        // stage Q chunk (16 d) transposed+swizzled: 1024 float4
#pragma unroll
        for (int i = 0; i < 4; ++i) {
            const int j   = t + 256 * i;
            const int row = j >> 2;           // 0..255
            const int dl4 = (j & 3) << 2;     // local d f4-group: 0,4,8,12
            const size_t g = ((size_t)(n * SEQ + l0 + row) * NH + h) * DIM + dc * 16 + dl4;
            float4 q4 = *(const float4*)(Qin + g);
            const int col = row ^ dl4;
            Qt[(dl4 + 0) * 256 + col] = elu1(q4.x);
            Qt[(dl4 + 1) * 256 + col] = elu1(q4.y);
            Qt[(dl4 + 2) * 256 + col] = elu1(q4.z);
            Qt[(dl4 + 3) * 256 + col] = elu1(q4.w);
        }
        __syncthreads();

#pragma unroll 2
        for (int dl = 0; dl < 16; ++dl) {
            const int d = dc * 16 + dl;
            const int s = dl & 12;
            float4 qa = *(const float4*)&Qt[dl * 256 + (r0 ^ s)];
            float4 qb = *(const float4*)&Qt[dl * 256 + ((r0 + 4) ^ s)];
            float4 ka = *(const float4*)&KVs[d][v0];
            float4 kb = *(const float4*)&KVs[d][v0 + 4];
            const float ksd = Kss[d];
            float q[8]  = {qa.x, qa.y, qa.z, qa.w, qb.x, qb.y, qb.z, qb.w};
            float kv[8] = {ka.x, ka.y, ka.z, ka.w, kb.x, kb.y, kb.z, kb.w};
#pragma unroll
            for (int i = 0; i < 8; ++i) {
                p[i] = fmaf(q[i], ksd, p[i]);
#pragma unroll
                for (int jj = 0; jj < 8; ++jj)
                    acc[i][jj] = fmaf(q[i], kv[jj], acc[i][jj]);
            }
        }
    }

    // epilogue: scale by 1/(p+eps), float4 stores
#pragma unroll
    for (int i = 0; i < 8; ++i) {
        const float z = 1.0f / (p[i] + 1e-6f);
        const int l = l0 + r0 + i;
        float* o = Out + ((size_t)(n * SEQ + l) * NH + h) * DIM + v0;
        float4 oa, ob;
        oa.x = acc[i][0] * z; oa.y = acc[i][1] * z; oa.z = acc[i][2] * z; oa.w = acc[i][3] * z;
        ob.x = acc[i][4] * z; ob.y = acc[i][5] * z; ob.z = acc[i][6] * z; ob.w = acc[i][7] * z;
        *(float4*)(o)     = oa;
        *(float4*)(o + 4) = ob;
    }
}

extern "C" void kernel_launch(void* const* d_in, const int* in_sizes, int n_in,
                              void* d_out, int out_size, void* d_ws, size_t ws_size,
                              hipStream_t stream) {
    const float* Q = (const float*)d_in[0];
    const float* K = (const float*)d_in[1];
    const float* V = (const float*)d_in[2];
    float* out = (float*)d_out;

    // ws layout: [KVf 32*4096][Ksf 32*64][pKV NC*32*4096][pKs NC*32*64]
    int NC = 64;  // grid = 4n * NC = 256 blocks of 512 thr -> all CUs busy
    const size_t unit = 133120ull * 4ull; // (4096+64)*32 floats in bytes
    while (NC > 1 && (size_t)(NC + 1) * unit > ws_size) NC >>= 1;
    const int sLen = SEQ / NC;

    float* KVf = (float*)d_ws;
    float* Ksf = KVf + 32 * 4096;
    float* pKV = Ksf + 32 * 64;
    float* pKs = pKV + (size_t)NC * 32 * 4096;

    hipLaunchKernelGGL(k_phase1, dim3(4 * NC), dim3(512), 0, stream, K, V, pKV, pKs, NC, sLen);
    switch (NC) {
        case 64: hipLaunchKernelGGL(k_reduceT<64>, dim3(256), dim3(128), 0, stream, pKV, pKs, KVf, Ksf); break;
        case 32: hipLaunchKernelGGL(k_reduceT<32>, dim3(256), dim3(128), 0, stream, pKV, pKs, KVf, Ksf); break;
        case 16: hipLaunchKernelGGL(k_reduceT<16>, dim3(256), dim3(128), 0, stream, pKV, pKs, KVf, Ksf); break;
        case 8:  hipLaunchKernelGGL(k_reduceT<8>,  dim3(256), dim3(128), 0, stream, pKV, pKs, KVf, Ksf); break;
        default: hipLaunchKernelGGL(k_reduceG, dim3(256), dim3(128), 0, stream, pKV, pKs, KVf, Ksf, NC); break;
    }
    hipLaunchKernelGGL(k_phase2, dim3(512), dim3(256), 0, stream, Q, KVf, Ksf, out);
}